// Round 6
// baseline (348.656 us; speedup 1.0000x reference)
//
#include <hip/hip_runtime.h>

#define BB 4
#define LL 1024
#define EE 1024
#define HH 16
#define HD 64
#define NBUCKET 33
#define SCALE 0.125f
#define SC2 (0.125f * 1.44269504088896f)

typedef unsigned short u16;
using f32x4 = __attribute__((ext_vector_type(4))) float;
using s16x8 = __attribute__((ext_vector_type(8))) short;

__device__ __forceinline__ u16 f2bf(float f) {
  union { float f; unsigned u; } x; x.f = f;
  unsigned r = (x.u + 0x7fffu + ((x.u >> 16) & 1u)) >> 16;
  return (u16)r;
}

__device__ __forceinline__ void gld_lds16(const void* g, void* s) {
  __builtin_amdgcn_global_load_lds((const __attribute__((address_space(1))) void*)g,
                                   (__attribute__((address_space(3))) void*)s, 16, 0, 0);
}

__device__ __forceinline__ float qsum16(float s) {
  s += __shfl_xor(s, 1); s += __shfl_xor(s, 2);
  s += __shfl_xor(s, 4); s += __shfl_xor(s, 8);
  return s;
}

// ---------------- fp32 -> bf16 convert ----------------
__global__ __launch_bounds__(256) void cvt_bf16(const float* __restrict__ in,
                                                u16* __restrict__ out, int n4) {
  int i = blockIdx.x * blockDim.x + threadIdx.x;
  if (i < n4) {
    float4 f = ((const float4*)in)[i];
    ushort4 o;
    o.x = f2bf(f.x); o.y = f2bf(f.y); o.z = f2bf(f.z); o.w = f2bf(f.w);
    ((ushort4*)out)[i] = o;
  }
}

// rel_k (33x64 f32) -> padded (48x64 bf16, zero fill)
__global__ __launch_bounds__(256) void cvt_relk(const float* __restrict__ in,
                                                u16* __restrict__ out) {
  int t = blockIdx.x * 256 + threadIdx.x;
  if (t < 48 * 64) out[t] = (t < 33 * 64) ? f2bf(in[t]) : (u16)0;
}

// ---------------- 128x128x64-tile bf16 GEMM, C = A * B^T + bias ----------------
template <int MODE>
__device__ __forceinline__ void gemm128_bt(const u16* __restrict__ A,
                                           const u16* __restrict__ Bw,
                                           const float* __restrict__ bias,
                                           u16* __restrict__ obf,
                                           float* __restrict__ ofp,
                                           int M, int N, int K, int m0, int n0) {
  __shared__ u16 a_sm[128 * 64];
  __shared__ u16 b_sm[128 * 64];
  const int tid = threadIdx.x;
  const int wave = tid >> 6, lane = tid & 63;
  const int row16 = lane & 15, quad = lane >> 4;
  const int wr = (wave >> 1) * 64, wc = (wave & 1) * 64;
  const int srow = lane >> 3, scol = (lane & 7) * 8;

  f32x4 acc[4][4] = {};

  for (int k0 = 0; k0 < K; k0 += 64) {
#pragma unroll
    for (int t = 0; t < 4; ++t) {
      const int chunk = wave * 4 + t;
      const int r = chunk * 8 + srow;
      gld_lds16(A + (size_t)(m0 + r) * K + k0 + scol, a_sm + chunk * 512);
      gld_lds16(Bw + (size_t)(n0 + r) * K + k0 + scol, b_sm + chunk * 512);
    }
    __syncthreads();
#pragma unroll
    for (int ks = 0; ks < 2; ++ks) {
      s16x8 af[4], bf[4];
#pragma unroll
      for (int mi = 0; mi < 4; ++mi)
        af[mi] = *(const s16x8*)&a_sm[(wr + mi * 16 + row16) * 64 + ks * 32 + quad * 8];
#pragma unroll
      for (int ni = 0; ni < 4; ++ni)
        bf[ni] = *(const s16x8*)&b_sm[(wc + ni * 16 + row16) * 64 + ks * 32 + quad * 8];
#pragma unroll
      for (int mi = 0; mi < 4; ++mi)
#pragma unroll
        for (int ni = 0; ni < 4; ++ni)
          acc[mi][ni] = __builtin_amdgcn_mfma_f32_16x16x32_bf16(af[mi], bf[ni], acc[mi][ni], 0, 0, 0);
    }
    __syncthreads();
  }

#pragma unroll
  for (int mi = 0; mi < 4; ++mi)
#pragma unroll
    for (int ni = 0; ni < 4; ++ni) {
      const int n = n0 + wc + ni * 16 + row16;
      const float bn = bias[n];
#pragma unroll
      for (int r = 0; r < 4; ++r) {
        const int m = m0 + wr + mi * 16 + quad * 4 + r;
        const float v = acc[mi][ni][r] + bn;
        if (MODE == 0) {
          const int b = m >> 10, l = m & 1023, h = n >> 6, hd = n & 63;
          obf[((size_t)((b * HH + h) * LL + l)) * HD + hd] = f2bf(v);
        } else {
          ofp[(size_t)m * N + n] = v;
        }
      }
    }
}

__global__ __launch_bounds__(256) void proj_gemm(
    const u16* __restrict__ xq, const u16* __restrict__ xk, const u16* __restrict__ xv,
    const u16* __restrict__ wqb, const u16* __restrict__ wkb, const u16* __restrict__ wvb,
    const float* __restrict__ bq, const float* __restrict__ bk, const float* __restrict__ bv,
    u16* __restrict__ oq, u16* __restrict__ ok, u16* __restrict__ ov) {
  const u16* A; const u16* Bw; const float* bias; u16* O;
  if (blockIdx.z == 0)      { A = xq; Bw = wqb; bias = bq; O = oq; }
  else if (blockIdx.z == 1) { A = xk; Bw = wkb; bias = bk; O = ok; }
  else                      { A = xv; Bw = wvb; bias = bv; O = ov; }
  gemm128_bt<0>(A, Bw, bias, O, nullptr, BB * LL, EE, EE, blockIdx.y * 128, blockIdx.x * 128);
}

__global__ __launch_bounds__(256) void out_gemm(const u16* __restrict__ Y,
                                                const u16* __restrict__ wob,
                                                const float* __restrict__ bo,
                                                float* __restrict__ out) {
  gemm128_bt<1>(Y, wob, bo, nullptr, out, BB * LL, EE, EE, blockIdx.y * 128, blockIdx.x * 128);
}

// ---------------- V transpose: (BH, L, HD) -> (BH, HD, L) ----------------
__global__ __launch_bounds__(256) void transpose_v(const u16* __restrict__ Vin,
                                                   u16* __restrict__ Vout) {
  __shared__ u16 t_sm[64][65];
  const int bh = blockIdx.y;
  const int l0 = blockIdx.x * 64;
  const u16* src = Vin + (size_t)bh * LL * HD + (size_t)l0 * HD;
  u16* dst = Vout + (size_t)bh * HD * LL + l0;
  const int tid = threadIdx.x;
#pragma unroll
  for (int it = 0; it < 16; ++it) {
    int idx = tid + it * 256;
    int r = idx >> 6, c = idx & 63;
    t_sm[r][c] = src[(size_t)r * HD + c];
  }
  __syncthreads();
#pragma unroll
  for (int it = 0; it < 16; ++it) {
    int idx = tid + it * 256;
    int d = idx >> 6, j = idx & 63;
    dst[(size_t)d * LL + j] = t_sm[j][d];
  }
}

// ---------------- fused attention ----------------
// grid 1024 (1D, XCD-swizzled: bh = blk & 63), block 256 (4 waves; wave w owns
// q-rows [i0+16w, i0+16w+16)). K/V fragments direct from global; no main-loop
// barriers. Round-5-proven per-element path for near-diagonal tiles; far tiles
// (all dr<=-16 or all dr>=16) use a uniform per-row bias held in registers
// sourced by __shfl from the qr-MFMA accumulator (NO LDS read — the LDS-read
// flavor of this cache failed in rounds 1-sub/3-sub; shuffle sidesteps it).
__global__ __launch_bounds__(256) void attn_fused(
    const u16* __restrict__ Q, const u16* __restrict__ Kb, const u16* __restrict__ Vt,
    const u16* __restrict__ RKp, const float* __restrict__ RV, u16* __restrict__ Y) {
  __shared__ __align__(16) float qr_sm[4][16 * 36];
  __shared__ __align__(16) float s_sm[4][16 * 36];
  __shared__ __align__(16) unsigned char pool[9216];  // p_w slices in loop; rv_sm in epilogue

  const int tid = threadIdx.x;
  const int wave = tid >> 6, lane = tid & 63;
  const int row16 = lane & 15, quad = lane >> 4;
  const int bh = blockIdx.x & 63;          // XCD swizzle: xcd = blk % 8 = bh % 8
  const int i0 = (blockIdx.x >> 6) * 64;
  const int wq0 = i0 + wave * 16;
  const u16* qp = Q + (size_t)bh * LL * HD;
  const u16* kp = Kb + (size_t)bh * LL * HD;
  const u16* vp = Vt + (size_t)bh * HD * LL;

  u16* p_w = (u16*)pool + wave * (16 * 72);
  float* qr_w = &qr_sm[wave][0];
  float* s_w = &s_sm[wave][0];

  for (int t = lane; t < 16 * 36; t += 64) s_w[t] = 0.f;

  // Q fragments (A-operand: m=lane&15, k=quad*8+j)
  s16x8 qf[2];
#pragma unroll
  for (int ks = 0; ks < 2; ++ks)
    qf[ks] = *(const s16x8*)(qp + (size_t)(wq0 + row16) * HD + ks * 32 + quad * 8);

  // qr[i][bucket] = q[i] . rel_k[bucket] (unscaled), buckets padded to 48.
  // Keep nt=0 and nt=2 accumulators for the register far-bias (buckets 0, 32).
  f32x4 a0, a2;
#pragma unroll
  for (int nt = 0; nt < 3; ++nt) {
    f32x4 a = {};
#pragma unroll
    for (int ks = 0; ks < 2; ++ks) {
      s16x8 bfr = *(const s16x8*)(RKp + (size_t)(nt * 16 + row16) * HD + ks * 32 + quad * 8);
      a = __builtin_amdgcn_mfma_f32_16x16x32_bf16(qf[ks], bfr, a, 0, 0, 0);
    }
    if (nt == 0) a0 = a;
    if (nt == 2) a2 = a;
    const int idx = nt * 16 + row16;
    if (idx < NBUCKET)
#pragma unroll
      for (int r = 0; r < 4; ++r) qr_w[(quad * 4 + r) * 36 + idx] = a[r];
  }
  // bucket 0 / 32 bias per row i=quad*4+r lives in lane (quad,row16=0)'s acc
  float blo[4], bhi[4];
#pragma unroll
  for (int r = 0; r < 4; ++r) {
    blo[r] = __shfl(a0[r], lane & 48);
    bhi[r] = __shfl(a2[r], lane & 48);
  }

  f32x4 oacc[4] = {};
  float rsum[4] = {0.f, 0.f, 0.f, 0.f};
  float plos[4] = {0.f, 0.f, 0.f, 0.f};
  float phis[4] = {0.f, 0.f, 0.f, 0.f};
  int dbase[4];
#pragma unroll
  for (int nt = 0; nt < 4; ++nt) dbase[nt] = nt * 16 + row16 - quad * 4 - wq0;

  for (int jt = 0; jt < 16; ++jt) {
    const int j0 = jt * 64;

    // K fragments (B-operand: n=key row, k=HD slice), direct from global
    s16x8 kfr[4][2];
#pragma unroll
    for (int nt2 = 0; nt2 < 4; ++nt2)
#pragma unroll
      for (int ks = 0; ks < 2; ++ks)
        kfr[nt2][ks] = *(const s16x8*)(kp + (size_t)(j0 + nt2 * 16 + row16) * HD + ks * 32 + quad * 8);

    // V fragments (B-operand: n=d, k=key) issued BEFORE the QK MFMAs so their
    // latency hides behind QK + softmax (consumed only at the PV MFMAs)
    s16x8 vf[4][2];
#pragma unroll
    for (int dt = 0; dt < 4; ++dt)
#pragma unroll
      for (int ks = 0; ks < 2; ++ks)
        vf[dt][ks] = *(const s16x8*)(vp + (size_t)(dt * 16 + row16) * LL + j0 + ks * 32 + quad * 8);

    // S = Q K^T (16 q-rows x 64 keys)
    f32x4 sacc[4] = {};
#pragma unroll
    for (int ks = 0; ks < 2; ++ks)
#pragma unroll
      for (int nt2 = 0; nt2 < 4; ++nt2)
        sacc[nt2] = __builtin_amdgcn_mfma_f32_16x16x32_bf16(qf[ks], kfr[nt2][ks], sacc[nt2], 0, 0, 0);

    // P = exp2((S + qr[bucket]) * SC2)
    float p[4][4];
    const bool far_lo = (wq0 >= j0 + 79);   // all dr <= -16  -> bucket 0
    const bool far_hi = (j0 >= wq0 + 31);   // all dr >= +16  -> bucket 32
    if (far_lo || far_hi) {
#pragma unroll
      for (int r = 0; r < 4; ++r) {
        const float bias = far_lo ? blo[r] : bhi[r];
        float acc = 0.f;
#pragma unroll
        for (int nt2 = 0; nt2 < 4; ++nt2) {
          const float pv = exp2f((sacc[nt2][r] + bias) * SC2);
          p[nt2][r] = pv;
          acc += pv;
        }
        rsum[r] += acc;
        if (far_lo) plos[r] += acc; else phis[r] += acc;
      }
    } else {
      // near-diagonal: round-5-proven per-element path, verbatim
#pragma unroll
      for (int nt2 = 0; nt2 < 4; ++nt2)
#pragma unroll
        for (int r = 0; r < 4; ++r) {
          const int dr = dbase[nt2] + j0 - r;
          int bk = dr < -16 ? -16 : (dr > 16 ? 16 : dr);
          bk += 16;
          const float bias = qr_w[(quad * 4 + r) * 36 + bk];
          const float pv = exp2f((sacc[nt2][r] + bias) * SC2);
          p[nt2][r] = pv;
          rsum[r] += pv;
          if (dr <= -16) plos[r] += pv;
          else if (dr >= 16) phis[r] += pv;
          else atomicAdd(&s_w[(quad * 4 + r) * 36 + bk], pv);
        }
    }

    // P: C-layout -> A-layout via per-wave LDS slice (in-wave ordering suffices)
#pragma unroll
    for (int nt2 = 0; nt2 < 4; ++nt2)
#pragma unroll
      for (int r = 0; r < 4; ++r)
        p_w[(quad * 4 + r) * 72 + nt2 * 16 + row16] = f2bf(p[nt2][r]);

#pragma unroll
    for (int ks = 0; ks < 2; ++ks) {
      const s16x8 pf = *(const s16x8*)&p_w[row16 * 72 + ks * 32 + quad * 8];
#pragma unroll
      for (int dt = 0; dt < 4; ++dt)
        oacc[dt] = __builtin_amdgcn_mfma_f32_16x16x32_bf16(pf, vf[dt][ks], oacc[dt], 0, 0, 0);
    }
  }

  // post-loop reductions (once, not per tile)
  float lacc[4], slo[4], shi[4];
#pragma unroll
  for (int r = 0; r < 4; ++r) {
    lacc[r] = qsum16(rsum[r]);
    slo[r] = qsum16(plos[r]);
    shi[r] = qsum16(phis[r]);
  }

  // epilogue: rel_v into pool (after barrier so all waves' p_w reads are done)
  __syncthreads();
  float* rv_sm = (float*)pool;
  for (int t = tid; t < NBUCKET * HD; t += 256) rv_sm[t] = RV[t];
  __syncthreads();

  const int b = bh >> 4, h = bh & 15;
#pragma unroll
  for (int r = 0; r < 4; ++r) {
    const int i_loc = quad * 4 + r;
    float rel[4] = {0.f, 0.f, 0.f, 0.f};
    for (int bk = 0; bk < NBUCKET; ++bk) {
      float sv = s_w[i_loc * 36 + bk];
      if (bk == 0) sv += slo[r];
      if (bk == 32) sv += shi[r];
#pragma unroll
      for (int dt = 0; dt < 4; ++dt) rel[dt] += sv * rv_sm[bk * HD + dt * 16 + row16];
    }
    const float inv = 1.0f / lacc[r];
#pragma unroll
    for (int dt = 0; dt < 4; ++dt) {
      const float y = (oacc[dt][r] + rel[dt]) * inv;
      Y[((size_t)(b * LL + wq0 + i_loc)) * EE + h * HD + dt * 16 + row16] = f2bf(y);
    }
  }
}

extern "C" void kernel_launch(void* const* d_in, const int* in_sizes, int n_in,
                              void* d_out, int out_size, void* d_ws, size_t ws_size,
                              hipStream_t stream) {
  const float* query = (const float*)d_in[0];
  const float* key_  = (const float*)d_in[1];
  const float* value = (const float*)d_in[2];
  const float* wq = (const float*)d_in[3];
  const float* bq = (const float*)d_in[4];
  const float* wk = (const float*)d_in[5];
  const float* bk = (const float*)d_in[6];
  const float* wv = (const float*)d_in[7];
  const float* bv = (const float*)d_in[8];
  const float* wo = (const float*)d_in[9];
  const float* bo = (const float*)d_in[10];
  const float* rel_k = (const float*)d_in[11];
  const float* rel_v = (const float*)d_in[12];

  char* base = (char*)d_ws;
  size_t off = 0;
  auto alloc = [&](size_t bytes) -> void* {
    void* p = base + off;
    off += (bytes + 255) & ~(size_t)255;
    return p;
  };
  const size_t XE = (size_t)BB * LL * EE;
  u16* xq    = (u16*)alloc(XE * 2);
  u16* xk    = (u16*)alloc(XE * 2);
  u16* xv    = (u16*)alloc(XE * 2);
  u16* wqb   = (u16*)alloc((size_t)EE * EE * 2);
  u16* wkb   = (u16*)alloc((size_t)EE * EE * 2);
  u16* wvb   = (u16*)alloc((size_t)EE * EE * 2);
  u16* wob   = (u16*)alloc((size_t)EE * EE * 2);
  u16* q_ws  = (u16*)alloc(XE * 2);
  u16* k_ws  = (u16*)alloc(XE * 2);
  u16* v_tmp = (u16*)alloc(XE * 2);
  u16* relkp = (u16*)alloc(48 * 64 * 2);
  u16* vt   = xk;   // dead after proj_gemm
  u16* y_ws = xq;   // dead after proj_gemm

  const int nx4 = (int)(XE / 4);
  const int nw4 = EE * EE / 4;
  cvt_bf16<<<nx4 / 256, 256, 0, stream>>>(query, xq, nx4);
  cvt_bf16<<<nx4 / 256, 256, 0, stream>>>(key_, xk, nx4);
  cvt_bf16<<<nx4 / 256, 256, 0, stream>>>(value, xv, nx4);
  cvt_bf16<<<nw4 / 256, 256, 0, stream>>>(wq, wqb, nw4);
  cvt_bf16<<<nw4 / 256, 256, 0, stream>>>(wk, wkb, nw4);
  cvt_bf16<<<nw4 / 256, 256, 0, stream>>>(wv, wvb, nw4);
  cvt_bf16<<<nw4 / 256, 256, 0, stream>>>(wo, wob, nw4);
  cvt_relk<<<12, 256, 0, stream>>>(rel_k, relkp);

  proj_gemm<<<dim3(EE / 128, BB * LL / 128, 3), 256, 0, stream>>>(
      xq, xk, xv, wqb, wkb, wvb, bq, bk, bv, q_ws, k_ws, v_tmp);

  transpose_v<<<dim3(LL / 64, BB * HH), 256, 0, stream>>>(v_tmp, vt);

  attn_fused<<<1024, 256, 0, stream>>>(q_ws, k_ws, vt, relkp, rel_v, y_ws);

  out_gemm<<<dim3(EE / 128, BB * LL / 128), 256, 0, stream>>>(y_ws, wob, bo, (float*)d_out);
}

// Round 7
// 348.646 us; speedup vs baseline: 1.0000x; 1.0000x over previous
//
#include <hip/hip_runtime.h>

#define BB 4
#define LL 1024
#define EE 1024
#define HH 16
#define HD 64
#define NBUCKET 33
#define SCALE 0.125f
#define SC2 (0.125f * 1.44269504088896f)

typedef unsigned short u16;
using f32x4 = __attribute__((ext_vector_type(4))) float;
using s16x8 = __attribute__((ext_vector_type(8))) short;

__device__ __forceinline__ u16 f2bf(float f) {
  union { float f; unsigned u; } x; x.f = f;
  unsigned r = (x.u + 0x7fffu + ((x.u >> 16) & 1u)) >> 16;
  return (u16)r;
}

__device__ __forceinline__ void gld_lds16(const void* g, void* s) {
  __builtin_amdgcn_global_load_lds((const __attribute__((address_space(1))) void*)g,
                                   (__attribute__((address_space(3))) void*)s, 16, 0, 0);
}

__device__ __forceinline__ float qsum16(float s) {
  s += __shfl_xor(s, 1); s += __shfl_xor(s, 2);
  s += __shfl_xor(s, 4); s += __shfl_xor(s, 8);
  return s;
}

// ---------------- fp32 -> bf16 converts (merged launches) ----------------
__global__ __launch_bounds__(256) void cvt3_bf16(const float* __restrict__ a,
                                                 const float* __restrict__ b,
                                                 const float* __restrict__ c,
                                                 u16* __restrict__ oa, u16* __restrict__ ob,
                                                 u16* __restrict__ oc, int n4) {
  const int z = blockIdx.y;
  const float* in = z == 0 ? a : (z == 1 ? b : c);
  u16* out = z == 0 ? oa : (z == 1 ? ob : oc);
  int i = blockIdx.x * 256 + threadIdx.x;
  if (i < n4) {
    float4 f = ((const float4*)in)[i];
    ushort4 o;
    o.x = f2bf(f.x); o.y = f2bf(f.y); o.z = f2bf(f.z); o.w = f2bf(f.w);
    ((ushort4*)out)[i] = o;
  }
}

__global__ __launch_bounds__(256) void cvt4_bf16(const float* __restrict__ a,
                                                 const float* __restrict__ b,
                                                 const float* __restrict__ c,
                                                 const float* __restrict__ d,
                                                 u16* __restrict__ oa, u16* __restrict__ ob,
                                                 u16* __restrict__ oc, u16* __restrict__ od,
                                                 int n4) {
  const int z = blockIdx.y;
  const float* in = z == 0 ? a : (z == 1 ? b : (z == 2 ? c : d));
  u16* out = z == 0 ? oa : (z == 1 ? ob : (z == 2 ? oc : od));
  int i = blockIdx.x * 256 + threadIdx.x;
  if (i < n4) {
    float4 f = ((const float4*)in)[i];
    ushort4 o;
    o.x = f2bf(f.x); o.y = f2bf(f.y); o.z = f2bf(f.z); o.w = f2bf(f.w);
    ((ushort4*)out)[i] = o;
  }
}

// rel_k (33x64 f32) -> padded (48x64 bf16, zero fill)
__global__ __launch_bounds__(256) void cvt_relk(const float* __restrict__ in,
                                                u16* __restrict__ out) {
  int t = blockIdx.x * 256 + threadIdx.x;
  if (t < 48 * 64) out[t] = (t < 33 * 64) ? f2bf(in[t]) : (u16)0;
}

// ---------------- 128x128x64-tile bf16 GEMM, C = A * B^T + bias ----------------
template <int MODE>
__device__ __forceinline__ void gemm128_bt(const u16* __restrict__ A,
                                           const u16* __restrict__ Bw,
                                           const float* __restrict__ bias,
                                           u16* __restrict__ obf,
                                           float* __restrict__ ofp,
                                           int M, int N, int K, int m0, int n0) {
  __shared__ u16 a_sm[128 * 64];
  __shared__ u16 b_sm[128 * 64];
  const int tid = threadIdx.x;
  const int wave = tid >> 6, lane = tid & 63;
  const int row16 = lane & 15, quad = lane >> 4;
  const int wr = (wave >> 1) * 64, wc = (wave & 1) * 64;
  const int srow = lane >> 3, scol = (lane & 7) * 8;

  f32x4 acc[4][4] = {};

  for (int k0 = 0; k0 < K; k0 += 64) {
#pragma unroll
    for (int t = 0; t < 4; ++t) {
      const int chunk = wave * 4 + t;
      const int r = chunk * 8 + srow;
      gld_lds16(A + (size_t)(m0 + r) * K + k0 + scol, a_sm + chunk * 512);
      gld_lds16(Bw + (size_t)(n0 + r) * K + k0 + scol, b_sm + chunk * 512);
    }
    __syncthreads();
#pragma unroll
    for (int ks = 0; ks < 2; ++ks) {
      s16x8 af[4], bf[4];
#pragma unroll
      for (int mi = 0; mi < 4; ++mi)
        af[mi] = *(const s16x8*)&a_sm[(wr + mi * 16 + row16) * 64 + ks * 32 + quad * 8];
#pragma unroll
      for (int ni = 0; ni < 4; ++ni)
        bf[ni] = *(const s16x8*)&b_sm[(wc + ni * 16 + row16) * 64 + ks * 32 + quad * 8];
#pragma unroll
      for (int mi = 0; mi < 4; ++mi)
#pragma unroll
        for (int ni = 0; ni < 4; ++ni)
          acc[mi][ni] = __builtin_amdgcn_mfma_f32_16x16x32_bf16(af[mi], bf[ni], acc[mi][ni], 0, 0, 0);
    }
    __syncthreads();
  }

#pragma unroll
  for (int mi = 0; mi < 4; ++mi)
#pragma unroll
    for (int ni = 0; ni < 4; ++ni) {
      const int n = n0 + wc + ni * 16 + row16;
      const float bn = bias[n];
#pragma unroll
      for (int r = 0; r < 4; ++r) {
        const int m = m0 + wr + mi * 16 + quad * 4 + r;
        const float v = acc[mi][ni][r] + bn;
        if (MODE == 0) {
          const int b = m >> 10, l = m & 1023, h = n >> 6, hd = n & 63;
          obf[((size_t)((b * HH + h) * LL + l)) * HD + hd] = f2bf(v);
        } else {
          ofp[(size_t)m * N + n] = v;
        }
      }
    }
}

__global__ __launch_bounds__(256) void proj_gemm(
    const u16* __restrict__ xq, const u16* __restrict__ xk, const u16* __restrict__ xv,
    const u16* __restrict__ wqb, const u16* __restrict__ wkb, const u16* __restrict__ wvb,
    const float* __restrict__ bq, const float* __restrict__ bk, const float* __restrict__ bv,
    u16* __restrict__ oq, u16* __restrict__ ok, u16* __restrict__ ov) {
  const u16* A; const u16* Bw; const float* bias; u16* O;
  if (blockIdx.z == 0)      { A = xq; Bw = wqb; bias = bq; O = oq; }
  else if (blockIdx.z == 1) { A = xk; Bw = wkb; bias = bk; O = ok; }
  else                      { A = xv; Bw = wvb; bias = bv; O = ov; }
  gemm128_bt<0>(A, Bw, bias, O, nullptr, BB * LL, EE, EE, blockIdx.y * 128, blockIdx.x * 128);
}

__global__ __launch_bounds__(256) void out_gemm(const u16* __restrict__ Y,
                                                const u16* __restrict__ wob,
                                                const float* __restrict__ bo,
                                                float* __restrict__ out) {
  gemm128_bt<1>(Y, wob, bo, nullptr, out, BB * LL, EE, EE, blockIdx.y * 128, blockIdx.x * 128);
}

// ---------------- V transpose: (BH, L, HD) -> (BH, HD, L) ----------------
__global__ __launch_bounds__(256) void transpose_v(const u16* __restrict__ Vin,
                                                   u16* __restrict__ Vout) {
  __shared__ u16 t_sm[64][65];
  const int bh = blockIdx.y;
  const int l0 = blockIdx.x * 64;
  const u16* src = Vin + (size_t)bh * LL * HD + (size_t)l0 * HD;
  u16* dst = Vout + (size_t)bh * HD * LL + l0;
  const int tid = threadIdx.x;
#pragma unroll
  for (int it = 0; it < 16; ++it) {
    int idx = tid + it * 256;
    int r = idx >> 6, c = idx & 63;
    t_sm[r][c] = src[(size_t)r * HD + c];
  }
  __syncthreads();
#pragma unroll
  for (int it = 0; it < 16; ++it) {
    int idx = tid + it * 256;
    int d = idx >> 6, j = idx & 63;
    dst[(size_t)d * LL + j] = t_sm[j][d];
  }
}

// ---------------- fused attention ----------------
// grid 1024 (1D, XCD-swizzled: bh = blk & 63), block 256 (4 waves; wave w owns
// q-rows [i0+16w, i0+16w+16)). K/V fragments direct from global; no main-loop
// barriers. Round-6-proven math (far-tile shfl-sourced bias + near-tile
// per-element path). NEW: K fragments software-pipelined one j-tile ahead
// (double-buffered registers, #pragma unroll 2 for compile-time jt&1) so the
// QK MFMA never waits on a just-issued load.
__global__ __launch_bounds__(256) void attn_fused(
    const u16* __restrict__ Q, const u16* __restrict__ Kb, const u16* __restrict__ Vt,
    const u16* __restrict__ RKp, const float* __restrict__ RV, u16* __restrict__ Y) {
  __shared__ __align__(16) float qr_sm[4][16 * 36];
  __shared__ __align__(16) float s_sm[4][16 * 36];
  __shared__ __align__(16) unsigned char pool[9216];  // p_w slices in loop; rv_sm in epilogue

  const int tid = threadIdx.x;
  const int wave = tid >> 6, lane = tid & 63;
  const int row16 = lane & 15, quad = lane >> 4;
  const int bh = blockIdx.x & 63;          // XCD swizzle: xcd = blk % 8 = bh % 8
  const int i0 = (blockIdx.x >> 6) * 64;
  const int wq0 = i0 + wave * 16;
  const u16* qp = Q + (size_t)bh * LL * HD;
  const u16* kp = Kb + (size_t)bh * LL * HD;
  const u16* vp = Vt + (size_t)bh * HD * LL;

  u16* p_w = (u16*)pool + wave * (16 * 72);
  float* qr_w = &qr_sm[wave][0];
  float* s_w = &s_sm[wave][0];

  for (int t = lane; t < 16 * 36; t += 64) s_w[t] = 0.f;

  // Q fragments (A-operand: m=lane&15, k=quad*8+j)
  s16x8 qf[2];
#pragma unroll
  for (int ks = 0; ks < 2; ++ks)
    qf[ks] = *(const s16x8*)(qp + (size_t)(wq0 + row16) * HD + ks * 32 + quad * 8);

  // qr[i][bucket] = q[i] . rel_k[bucket] (unscaled), buckets padded to 48.
  // Keep nt=0 and nt=2 accumulators for the register far-bias (buckets 0, 32).
  f32x4 a0, a2;
#pragma unroll
  for (int nt = 0; nt < 3; ++nt) {
    f32x4 a = {};
#pragma unroll
    for (int ks = 0; ks < 2; ++ks) {
      s16x8 bfr = *(const s16x8*)(RKp + (size_t)(nt * 16 + row16) * HD + ks * 32 + quad * 8);
      a = __builtin_amdgcn_mfma_f32_16x16x32_bf16(qf[ks], bfr, a, 0, 0, 0);
    }
    if (nt == 0) a0 = a;
    if (nt == 2) a2 = a;
    const int idx = nt * 16 + row16;
    if (idx < NBUCKET)
#pragma unroll
      for (int r = 0; r < 4; ++r) qr_w[(quad * 4 + r) * 36 + idx] = a[r];
  }
  // bucket 0 / 32 bias per row i=quad*4+r lives in lane (quad,row16=0)'s acc
  float blo[4], bhi[4];
#pragma unroll
  for (int r = 0; r < 4; ++r) {
    blo[r] = __shfl(a0[r], lane & 48);
    bhi[r] = __shfl(a2[r], lane & 48);
  }

  f32x4 oacc[4] = {};
  float rsum[4] = {0.f, 0.f, 0.f, 0.f};
  float plos[4] = {0.f, 0.f, 0.f, 0.f};
  float phis[4] = {0.f, 0.f, 0.f, 0.f};
  int dbase[4];
#pragma unroll
  for (int nt = 0; nt < 4; ++nt) dbase[nt] = nt * 16 + row16 - quad * 4 - wq0;

  // K fragment double-buffer: preload tile 0
  s16x8 kfr[2][4][2];
#pragma unroll
  for (int nt2 = 0; nt2 < 4; ++nt2)
#pragma unroll
    for (int ks = 0; ks < 2; ++ks)
      kfr[0][nt2][ks] = *(const s16x8*)(kp + (size_t)(nt2 * 16 + row16) * HD + ks * 32 + quad * 8);

#pragma unroll 2
  for (int jt = 0; jt < 16; ++jt) {
    const int j0 = jt * 64;
    const int cur = jt & 1;

    // V fragments (B-operand: n=d, k=key) for THIS tile — consumed only at the
    // PV MFMAs, so QK + softmax cover their latency
    s16x8 vf[4][2];
#pragma unroll
    for (int dt = 0; dt < 4; ++dt)
#pragma unroll
      for (int ks = 0; ks < 2; ++ks)
        vf[dt][ks] = *(const s16x8*)(vp + (size_t)(dt * 16 + row16) * LL + j0 + ks * 32 + quad * 8);

    // Prefetch NEXT tile's K fragments (consumed one iteration from now;
    // (jt+1)&15 wraps to tile 0 on the last iteration — valid memory, result unused)
    const int jn0 = ((jt + 1) & 15) * 64;
#pragma unroll
    for (int nt2 = 0; nt2 < 4; ++nt2)
#pragma unroll
      for (int ks = 0; ks < 2; ++ks)
        kfr[cur ^ 1][nt2][ks] =
            *(const s16x8*)(kp + (size_t)(jn0 + nt2 * 16 + row16) * HD + ks * 32 + quad * 8);

    // S = Q K^T (16 q-rows x 64 keys) using the PREfetched current buffer
    f32x4 sacc[4] = {};
#pragma unroll
    for (int ks = 0; ks < 2; ++ks)
#pragma unroll
      for (int nt2 = 0; nt2 < 4; ++nt2)
        sacc[nt2] = __builtin_amdgcn_mfma_f32_16x16x32_bf16(qf[ks], kfr[cur][nt2][ks], sacc[nt2], 0, 0, 0);

    // P = exp2((S + qr[bucket]) * SC2)
    float p[4][4];
    const bool far_lo = (wq0 >= j0 + 79);   // all dr <= -16  -> bucket 0
    const bool far_hi = (j0 >= wq0 + 31);   // all dr >= +16  -> bucket 32
    if (far_lo || far_hi) {
#pragma unroll
      for (int r = 0; r < 4; ++r) {
        const float bias = far_lo ? blo[r] : bhi[r];
        float acc = 0.f;
#pragma unroll
        for (int nt2 = 0; nt2 < 4; ++nt2) {
          const float pv = exp2f((sacc[nt2][r] + bias) * SC2);
          p[nt2][r] = pv;
          acc += pv;
        }
        rsum[r] += acc;
        if (far_lo) plos[r] += acc; else phis[r] += acc;
      }
    } else {
      // near-diagonal: per-element path (round-5/6-proven verbatim)
#pragma unroll
      for (int nt2 = 0; nt2 < 4; ++nt2)
#pragma unroll
        for (int r = 0; r < 4; ++r) {
          const int dr = dbase[nt2] + j0 - r;
          int bk = dr < -16 ? -16 : (dr > 16 ? 16 : dr);
          bk += 16;
          const float bias = qr_w[(quad * 4 + r) * 36 + bk];
          const float pv = exp2f((sacc[nt2][r] + bias) * SC2);
          p[nt2][r] = pv;
          rsum[r] += pv;
          if (dr <= -16) plos[r] += pv;
          else if (dr >= 16) phis[r] += pv;
          else atomicAdd(&s_w[(quad * 4 + r) * 36 + bk], pv);
        }
    }

    // P: C-layout -> A-layout via per-wave LDS slice (in-wave ordering suffices)
#pragma unroll
    for (int nt2 = 0; nt2 < 4; ++nt2)
#pragma unroll
      for (int r = 0; r < 4; ++r)
        p_w[(quad * 4 + r) * 72 + nt2 * 16 + row16] = f2bf(p[nt2][r]);

#pragma unroll
    for (int ks = 0; ks < 2; ++ks) {
      const s16x8 pf = *(const s16x8*)&p_w[row16 * 72 + ks * 32 + quad * 8];
#pragma unroll
      for (int dt = 0; dt < 4; ++dt)
        oacc[dt] = __builtin_amdgcn_mfma_f32_16x16x32_bf16(pf, vf[dt][ks], oacc[dt], 0, 0, 0);
    }
  }

  // post-loop reductions (once, not per tile)
  float lacc[4], slo[4], shi[4];
#pragma unroll
  for (int r = 0; r < 4; ++r) {
    lacc[r] = qsum16(rsum[r]);
    slo[r] = qsum16(plos[r]);
    shi[r] = qsum16(phis[r]);
  }

  // epilogue: rel_v into pool (after barrier so all waves' p_w reads are done)
  __syncthreads();
  float* rv_sm = (float*)pool;
  for (int t = tid; t < NBUCKET * HD; t += 256) rv_sm[t] = RV[t];
  __syncthreads();

  const int b = bh >> 4, h = bh & 15;
#pragma unroll
  for (int r = 0; r < 4; ++r) {
    const int i_loc = quad * 4 + r;
    float rel[4] = {0.f, 0.f, 0.f, 0.f};
    for (int bk = 0; bk < NBUCKET; ++bk) {
      float sv = s_w[i_loc * 36 + bk];
      if (bk == 0) sv += slo[r];
      if (bk == 32) sv += shi[r];
#pragma unroll
      for (int dt = 0; dt < 4; ++dt) rel[dt] += sv * rv_sm[bk * HD + dt * 16 + row16];
    }
    const float inv = 1.0f / lacc[r];
#pragma unroll
    for (int dt = 0; dt < 4; ++dt) {
      const float y = (oacc[dt][r] + rel[dt]) * inv;
      Y[((size_t)(b * LL + wq0 + i_loc)) * EE + h * HD + dt * 16 + row16] = f2bf(y);
    }
  }
}

extern "C" void kernel_launch(void* const* d_in, const int* in_sizes, int n_in,
                              void* d_out, int out_size, void* d_ws, size_t ws_size,
                              hipStream_t stream) {
  const float* query = (const float*)d_in[0];
  const float* key_  = (const float*)d_in[1];
  const float* value = (const float*)d_in[2];
  const float* wq = (const float*)d_in[3];
  const float* bq = (const float*)d_in[4];
  const float* wk = (const float*)d_in[5];
  const float* bk = (const float*)d_in[6];
  const float* wv = (const float*)d_in[7];
  const float* bv = (const float*)d_in[8];
  const float* wo = (const float*)d_in[9];
  const float* bo = (const float*)d_in[10];
  const float* rel_k = (const float*)d_in[11];
  const float* rel_v = (const float*)d_in[12];

  char* base = (char*)d_ws;
  size_t off = 0;
  auto alloc = [&](size_t bytes) -> void* {
    void* p = base + off;
    off += (bytes + 255) & ~(size_t)255;
    return p;
  };
  const size_t XE = (size_t)BB * LL * EE;
  u16* xq    = (u16*)alloc(XE * 2);
  u16* xk    = (u16*)alloc(XE * 2);
  u16* xv    = (u16*)alloc(XE * 2);
  u16* wqb   = (u16*)alloc((size_t)EE * EE * 2);
  u16* wkb   = (u16*)alloc((size_t)EE * EE * 2);
  u16* wvb   = (u16*)alloc((size_t)EE * EE * 2);
  u16* wob   = (u16*)alloc((size_t)EE * EE * 2);
  u16* q_ws  = (u16*)alloc(XE * 2);
  u16* k_ws  = (u16*)alloc(XE * 2);
  u16* v_tmp = (u16*)alloc(XE * 2);
  u16* relkp = (u16*)alloc(48 * 64 * 2);
  u16* vt   = xk;   // dead after proj_gemm
  u16* y_ws = xq;   // dead after proj_gemm

  const int nx4 = (int)(XE / 4);
  const int nw4 = EE * EE / 4;
  cvt3_bf16<<<dim3(nx4 / 256, 3), 256, 0, stream>>>(query, key_, value, xq, xk, xv, nx4);
  cvt4_bf16<<<dim3(nw4 / 256, 4), 256, 0, stream>>>(wq, wk, wv, wo, wqb, wkb, wvb, wob, nw4);
  cvt_relk<<<12, 256, 0, stream>>>(rel_k, relkp);

  proj_gemm<<<dim3(EE / 128, BB * LL / 128, 3), 256, 0, stream>>>(
      xq, xk, xv, wqb, wkb, wvb, bq, bk, bv, q_ws, k_ws, v_tmp);

  transpose_v<<<dim3(LL / 64, BB * HH), 256, 0, stream>>>(v_tmp, vt);

  attn_fused<<<1024, 256, 0, stream>>>(q_ws, k_ws, vt, relkp, rel_v, y_ws);

  out_gemm<<<dim3(EE / 128, BB * LL / 128), 256, 0, stream>>>(y_ws, wob, bo, (float*)d_out);
}

// Round 8
// 333.184 us; speedup vs baseline: 1.0464x; 1.0464x over previous
//
#include <hip/hip_runtime.h>

#define BB 4
#define LL 1024
#define EE 1024
#define HH 16
#define HD 64
#define NBUCKET 33
#define SCALE 0.125f
#define SC2 (0.125f * 1.44269504088896f)

typedef unsigned short u16;
using f32x4 = __attribute__((ext_vector_type(4))) float;
using s16x8 = __attribute__((ext_vector_type(8))) short;

__device__ __forceinline__ u16 f2bf(float f) {
  union { float f; unsigned u; } x; x.f = f;
  unsigned r = (x.u + 0x7fffu + ((x.u >> 16) & 1u)) >> 16;
  return (u16)r;
}

__device__ __forceinline__ void gld_lds16(const void* g, void* s) {
  __builtin_amdgcn_global_load_lds((const __attribute__((address_space(1))) void*)g,
                                   (__attribute__((address_space(3))) void*)s, 16, 0, 0);
}

__device__ __forceinline__ float qsum16(float s) {
  s += __shfl_xor(s, 1); s += __shfl_xor(s, 2);
  s += __shfl_xor(s, 4); s += __shfl_xor(s, 8);
  return s;
}

// ---------------- fp32 -> bf16 converts (merged launches) ----------------
__global__ __launch_bounds__(256) void cvt3_bf16(const float* __restrict__ a,
                                                 const float* __restrict__ b,
                                                 const float* __restrict__ c,
                                                 u16* __restrict__ oa, u16* __restrict__ ob,
                                                 u16* __restrict__ oc, int n4) {
  const int z = blockIdx.y;
  const float* in = z == 0 ? a : (z == 1 ? b : c);
  u16* out = z == 0 ? oa : (z == 1 ? ob : oc);
  int i = blockIdx.x * 256 + threadIdx.x;
  if (i < n4) {
    float4 f = ((const float4*)in)[i];
    ushort4 o;
    o.x = f2bf(f.x); o.y = f2bf(f.y); o.z = f2bf(f.z); o.w = f2bf(f.w);
    ((ushort4*)out)[i] = o;
  }
}

// z=0..3: 4 weight matrices; z=4: rel_k (33x64 f32) -> padded (48x64 bf16)
__global__ __launch_bounds__(256) void cvt4r_bf16(const float* __restrict__ a,
                                                  const float* __restrict__ b,
                                                  const float* __restrict__ c,
                                                  const float* __restrict__ d,
                                                  const float* __restrict__ rk,
                                                  u16* __restrict__ oa, u16* __restrict__ ob,
                                                  u16* __restrict__ oc, u16* __restrict__ od,
                                                  u16* __restrict__ ork, int n4) {
  const int z = blockIdx.z;
  int i = blockIdx.x * 256 + threadIdx.x;
  if (z == 4) {
    if (i < 48 * 64) ork[i] = (i < 33 * 64) ? f2bf(rk[i]) : (u16)0;
    return;
  }
  const float* in = z == 0 ? a : (z == 1 ? b : (z == 2 ? c : d));
  u16* out = z == 0 ? oa : (z == 1 ? ob : (z == 2 ? oc : od));
  if (i < n4) {
    float4 f = ((const float4*)in)[i];
    ushort4 o;
    o.x = f2bf(f.x); o.y = f2bf(f.y); o.z = f2bf(f.z); o.w = f2bf(f.w);
    ((ushort4*)out)[i] = o;
  }
}

// ---------------- 128x128x64-tile bf16 GEMM, C = A * B^T + bias ----------------
// MODE 0: store bf16 head-layout (B,H,L,HD).
// MODE 1: store fp32 row-major [M][N].
// MODE 2: store bf16 transposed head-layout (B,H,HD,L) — packed ushort4 across r.
template <int MODE>
__device__ __forceinline__ void gemm128_bt(const u16* __restrict__ A,
                                           const u16* __restrict__ Bw,
                                           const float* __restrict__ bias,
                                           u16* __restrict__ obf,
                                           float* __restrict__ ofp,
                                           int M, int N, int K, int m0, int n0) {
  __shared__ u16 a_sm[128 * 64];
  __shared__ u16 b_sm[128 * 64];
  const int tid = threadIdx.x;
  const int wave = tid >> 6, lane = tid & 63;
  const int row16 = lane & 15, quad = lane >> 4;
  const int wr = (wave >> 1) * 64, wc = (wave & 1) * 64;
  const int srow = lane >> 3, scol = (lane & 7) * 8;

  f32x4 acc[4][4] = {};

  for (int k0 = 0; k0 < K; k0 += 64) {
#pragma unroll
    for (int t = 0; t < 4; ++t) {
      const int chunk = wave * 4 + t;
      const int r = chunk * 8 + srow;
      gld_lds16(A + (size_t)(m0 + r) * K + k0 + scol, a_sm + chunk * 512);
      gld_lds16(Bw + (size_t)(n0 + r) * K + k0 + scol, b_sm + chunk * 512);
    }
    __syncthreads();
#pragma unroll
    for (int ks = 0; ks < 2; ++ks) {
      s16x8 af[4], bf[4];
#pragma unroll
      for (int mi = 0; mi < 4; ++mi)
        af[mi] = *(const s16x8*)&a_sm[(wr + mi * 16 + row16) * 64 + ks * 32 + quad * 8];
#pragma unroll
      for (int ni = 0; ni < 4; ++ni)
        bf[ni] = *(const s16x8*)&b_sm[(wc + ni * 16 + row16) * 64 + ks * 32 + quad * 8];
#pragma unroll
      for (int mi = 0; mi < 4; ++mi)
#pragma unroll
        for (int ni = 0; ni < 4; ++ni)
          acc[mi][ni] = __builtin_amdgcn_mfma_f32_16x16x32_bf16(af[mi], bf[ni], acc[mi][ni], 0, 0, 0);
    }
    __syncthreads();
  }

#pragma unroll
  for (int mi = 0; mi < 4; ++mi)
#pragma unroll
    for (int ni = 0; ni < 4; ++ni) {
      const int n = n0 + wc + ni * 16 + row16;
      const float bn = bias[n];
      if (MODE == 2) {
        // rows r=0..3 are consecutive l -> one packed ushort4 store
        const int mr0 = m0 + wr + mi * 16 + quad * 4;
        const int b = mr0 >> 10, l = mr0 & 1023;
        const int h = n >> 6, hd = n & 63;
        ushort4 o;
        o.x = f2bf(acc[mi][ni][0] + bn);
        o.y = f2bf(acc[mi][ni][1] + bn);
        o.z = f2bf(acc[mi][ni][2] + bn);
        o.w = f2bf(acc[mi][ni][3] + bn);
        *(ushort4*)&obf[((size_t)((b * HH + h) * HD + hd)) * LL + l] = o;
      } else {
#pragma unroll
        for (int r = 0; r < 4; ++r) {
          const int m = m0 + wr + mi * 16 + quad * 4 + r;
          const float v = acc[mi][ni][r] + bn;
          if (MODE == 0) {
            const int b = m >> 10, l = m & 1023, h = n >> 6, hd = n & 63;
            obf[((size_t)((b * HH + h) * LL + l)) * HD + hd] = f2bf(v);
          } else {
            ofp[(size_t)m * N + n] = v;
          }
        }
      }
    }
}

__global__ __launch_bounds__(256) void proj_gemm(
    const u16* __restrict__ xq, const u16* __restrict__ xk, const u16* __restrict__ xv,
    const u16* __restrict__ wqb, const u16* __restrict__ wkb, const u16* __restrict__ wvb,
    const float* __restrict__ bq, const float* __restrict__ bk, const float* __restrict__ bv,
    u16* __restrict__ oq, u16* __restrict__ ok, u16* __restrict__ ovt) {
  if (blockIdx.z == 0)
    gemm128_bt<0>(xq, wqb, bq, oq, nullptr, BB * LL, EE, EE, blockIdx.y * 128, blockIdx.x * 128);
  else if (blockIdx.z == 1)
    gemm128_bt<0>(xk, wkb, bk, ok, nullptr, BB * LL, EE, EE, blockIdx.y * 128, blockIdx.x * 128);
  else  // V: store directly transposed (B,H,HD,L) — transpose_v kernel eliminated
    gemm128_bt<2>(xv, wvb, bv, ovt, nullptr, BB * LL, EE, EE, blockIdx.y * 128, blockIdx.x * 128);
}

__global__ __launch_bounds__(256) void out_gemm(const u16* __restrict__ Y,
                                                const u16* __restrict__ wob,
                                                const float* __restrict__ bo,
                                                float* __restrict__ out) {
  gemm128_bt<1>(Y, wob, bo, nullptr, out, BB * LL, EE, EE, blockIdx.y * 128, blockIdx.x * 128);
}

// ---------------- fused attention (round-6-proven, verbatim) ----------------
// grid 1024 (1D, XCD-swizzled: bh = blk & 63), block 256 (4 waves; wave w owns
// q-rows [i0+16w, i0+16w+16)). K/V fragments direct from global; no main-loop
// barriers. Far-tile shfl-sourced bias + near-tile per-element path.
// NOTE: VGPR=120 sits just under the 128 occupancy cliff (m69) — register-
// hungry pipelining here is net-negative (round-7 evidence: 152 VGPR halved
// occupancy, 142->155 us).
__global__ __launch_bounds__(256) void attn_fused(
    const u16* __restrict__ Q, const u16* __restrict__ Kb, const u16* __restrict__ Vt,
    const u16* __restrict__ RKp, const float* __restrict__ RV, u16* __restrict__ Y) {
  __shared__ __align__(16) float qr_sm[4][16 * 36];
  __shared__ __align__(16) float s_sm[4][16 * 36];
  __shared__ __align__(16) unsigned char pool[9216];  // p_w slices in loop; rv_sm in epilogue

  const int tid = threadIdx.x;
  const int wave = tid >> 6, lane = tid & 63;
  const int row16 = lane & 15, quad = lane >> 4;
  const int bh = blockIdx.x & 63;          // XCD swizzle: xcd = blk % 8 = bh % 8
  const int i0 = (blockIdx.x >> 6) * 64;
  const int wq0 = i0 + wave * 16;
  const u16* qp = Q + (size_t)bh * LL * HD;
  const u16* kp = Kb + (size_t)bh * LL * HD;
  const u16* vp = Vt + (size_t)bh * HD * LL;

  u16* p_w = (u16*)pool + wave * (16 * 72);
  float* qr_w = &qr_sm[wave][0];
  float* s_w = &s_sm[wave][0];

  for (int t = lane; t < 16 * 36; t += 64) s_w[t] = 0.f;

  // Q fragments (A-operand: m=lane&15, k=quad*8+j)
  s16x8 qf[2];
#pragma unroll
  for (int ks = 0; ks < 2; ++ks)
    qf[ks] = *(const s16x8*)(qp + (size_t)(wq0 + row16) * HD + ks * 32 + quad * 8);

  // qr[i][bucket] = q[i] . rel_k[bucket] (unscaled), buckets padded to 48.
  // Keep nt=0 and nt=2 accumulators for the register far-bias (buckets 0, 32).
  f32x4 a0, a2;
#pragma unroll
  for (int nt = 0; nt < 3; ++nt) {
    f32x4 a = {};
#pragma unroll
    for (int ks = 0; ks < 2; ++ks) {
      s16x8 bfr = *(const s16x8*)(RKp + (size_t)(nt * 16 + row16) * HD + ks * 32 + quad * 8);
      a = __builtin_amdgcn_mfma_f32_16x16x32_bf16(qf[ks], bfr, a, 0, 0, 0);
    }
    if (nt == 0) a0 = a;
    if (nt == 2) a2 = a;
    const int idx = nt * 16 + row16;
    if (idx < NBUCKET)
#pragma unroll
      for (int r = 0; r < 4; ++r) qr_w[(quad * 4 + r) * 36 + idx] = a[r];
  }
  // bucket 0 / 32 bias per row i=quad*4+r lives in lane (quad,row16=0)'s acc
  float blo[4], bhi[4];
#pragma unroll
  for (int r = 0; r < 4; ++r) {
    blo[r] = __shfl(a0[r], lane & 48);
    bhi[r] = __shfl(a2[r], lane & 48);
  }

  f32x4 oacc[4] = {};
  float rsum[4] = {0.f, 0.f, 0.f, 0.f};
  float plos[4] = {0.f, 0.f, 0.f, 0.f};
  float phis[4] = {0.f, 0.f, 0.f, 0.f};
  int dbase[4];
#pragma unroll
  for (int nt = 0; nt < 4; ++nt) dbase[nt] = nt * 16 + row16 - quad * 4 - wq0;

  for (int jt = 0; jt < 16; ++jt) {
    const int j0 = jt * 64;

    // K fragments (B-operand: n=key row, k=HD slice), direct from global
    s16x8 kfr[4][2];
#pragma unroll
    for (int nt2 = 0; nt2 < 4; ++nt2)
#pragma unroll
      for (int ks = 0; ks < 2; ++ks)
        kfr[nt2][ks] = *(const s16x8*)(kp + (size_t)(j0 + nt2 * 16 + row16) * HD + ks * 32 + quad * 8);

    // V fragments (B-operand: n=d, k=key) issued BEFORE the QK MFMAs so their
    // latency hides behind QK + softmax (consumed only at the PV MFMAs)
    s16x8 vf[4][2];
#pragma unroll
    for (int dt = 0; dt < 4; ++dt)
#pragma unroll
      for (int ks = 0; ks < 2; ++ks)
        vf[dt][ks] = *(const s16x8*)(vp + (size_t)(dt * 16 + row16) * LL + j0 + ks * 32 + quad * 8);

    // S = Q K^T (16 q-rows x 64 keys)
    f32x4 sacc[4] = {};
#pragma unroll
    for (int ks = 0; ks < 2; ++ks)
#pragma unroll
      for (int nt2 = 0; nt2 < 4; ++nt2)
        sacc[nt2] = __builtin_amdgcn_mfma_f32_16x16x32_bf16(qf[ks], kfr[nt2][ks], sacc[nt2], 0, 0, 0);

    // P = exp2((S + qr[bucket]) * SC2)
    float p[4][4];
    const bool far_lo = (wq0 >= j0 + 79);   // all dr <= -16  -> bucket 0
    const bool far_hi = (j0 >= wq0 + 31);   // all dr >= +16  -> bucket 32
    if (far_lo || far_hi) {
#pragma unroll
      for (int r = 0; r < 4; ++r) {
        const float bias = far_lo ? blo[r] : bhi[r];
        float acc = 0.f;
#pragma unroll
        for (int nt2 = 0; nt2 < 4; ++nt2) {
          const float pv = exp2f((sacc[nt2][r] + bias) * SC2);
          p[nt2][r] = pv;
          acc += pv;
        }
        rsum[r] += acc;
        if (far_lo) plos[r] += acc; else phis[r] += acc;
      }
    } else {
      // near-diagonal: per-element path (round-5/6-proven verbatim)
#pragma unroll
      for (int nt2 = 0; nt2 < 4; ++nt2)
#pragma unroll
        for (int r = 0; r < 4; ++r) {
          const int dr = dbase[nt2] + j0 - r;
          int bk = dr < -16 ? -16 : (dr > 16 ? 16 : dr);
          bk += 16;
          const float bias = qr_w[(quad * 4 + r) * 36 + bk];
          const float pv = exp2f((sacc[nt2][r] + bias) * SC2);
          p[nt2][r] = pv;
          rsum[r] += pv;
          if (dr <= -16) plos[r] += pv;
          else if (dr >= 16) phis[r] += pv;
          else atomicAdd(&s_w[(quad * 4 + r) * 36 + bk], pv);
        }
    }

    // P: C-layout -> A-layout via per-wave LDS slice (in-wave ordering suffices)
#pragma unroll
    for (int nt2 = 0; nt2 < 4; ++nt2)
#pragma unroll
      for (int r = 0; r < 4; ++r)
        p_w[(quad * 4 + r) * 72 + nt2 * 16 + row16] = f2bf(p[nt2][r]);

#pragma unroll
    for (int ks = 0; ks < 2; ++ks) {
      const s16x8 pf = *(const s16x8*)&p_w[row16 * 72 + ks * 32 + quad * 8];
#pragma unroll
      for (int dt = 0; dt < 4; ++dt)
        oacc[dt] = __builtin_amdgcn_mfma_f32_16x16x32_bf16(pf, vf[dt][ks], oacc[dt], 0, 0, 0);
    }
  }

  // post-loop reductions (once, not per tile)
  float lacc[4], slo[4], shi[4];
#pragma unroll
  for (int r = 0; r < 4; ++r) {
    lacc[r] = qsum16(rsum[r]);
    slo[r] = qsum16(plos[r]);
    shi[r] = qsum16(phis[r]);
  }

  // epilogue: rel_v into pool (after barrier so all waves' p_w reads are done)
  __syncthreads();
  float* rv_sm = (float*)pool;
  for (int t = tid; t < NBUCKET * HD; t += 256) rv_sm[t] = RV[t];
  __syncthreads();

  const int b = bh >> 4, h = bh & 15;
#pragma unroll
  for (int r = 0; r < 4; ++r) {
    const int i_loc = quad * 4 + r;
    float rel[4] = {0.f, 0.f, 0.f, 0.f};
    for (int bk = 0; bk < NBUCKET; ++bk) {
      float sv = s_w[i_loc * 36 + bk];
      if (bk == 0) sv += slo[r];
      if (bk == 32) sv += shi[r];
#pragma unroll
      for (int dt = 0; dt < 4; ++dt) rel[dt] += sv * rv_sm[bk * HD + dt * 16 + row16];
    }
    const float inv = 1.0f / lacc[r];
#pragma unroll
    for (int dt = 0; dt < 4; ++dt) {
      const float y = (oacc[dt][r] + rel[dt]) * inv;
      Y[((size_t)(b * LL + wq0 + i_loc)) * EE + h * HD + dt * 16 + row16] = f2bf(y);
    }
  }
}

extern "C" void kernel_launch(void* const* d_in, const int* in_sizes, int n_in,
                              void* d_out, int out_size, void* d_ws, size_t ws_size,
                              hipStream_t stream) {
  const float* query = (const float*)d_in[0];
  const float* key_  = (const float*)d_in[1];
  const float* value = (const float*)d_in[2];
  const float* wq = (const float*)d_in[3];
  const float* bq = (const float*)d_in[4];
  const float* wk = (const float*)d_in[5];
  const float* bk = (const float*)d_in[6];
  const float* wv = (const float*)d_in[7];
  const float* bv = (const float*)d_in[8];
  const float* wo = (const float*)d_in[9];
  const float* bo = (const float*)d_in[10];
  const float* rel_k = (const float*)d_in[11];
  const float* rel_v = (const float*)d_in[12];

  char* base = (char*)d_ws;
  size_t off = 0;
  auto alloc = [&](size_t bytes) -> void* {
    void* p = base + off;
    off += (bytes + 255) & ~(size_t)255;
    return p;
  };
  const size_t XE = (size_t)BB * LL * EE;
  u16* xq    = (u16*)alloc(XE * 2);
  u16* xk    = (u16*)alloc(XE * 2);
  u16* xv    = (u16*)alloc(XE * 2);
  u16* wqb   = (u16*)alloc((size_t)EE * EE * 2);
  u16* wkb   = (u16*)alloc((size_t)EE * EE * 2);
  u16* wvb   = (u16*)alloc((size_t)EE * EE * 2);
  u16* wob   = (u16*)alloc((size_t)EE * EE * 2);
  u16* q_ws  = (u16*)alloc(XE * 2);
  u16* k_ws  = (u16*)alloc(XE * 2);
  u16* vt_ws = (u16*)alloc(XE * 2);   // V stored transposed by proj_gemm
  u16* relkp = (u16*)alloc(48 * 64 * 2);
  u16* y_ws = xq;   // xq dead after proj_gemm (stream-ordered)

  const int nx4 = (int)(XE / 4);
  const int nw4 = EE * EE / 4;
  cvt3_bf16<<<dim3(nx4 / 256, 3), 256, 0, stream>>>(query, key_, value, xq, xk, xv, nx4);
  cvt4r_bf16<<<dim3(nw4 / 256, 1, 5), 256, 0, stream>>>(wq, wk, wv, wo, rel_k,
                                                        wqb, wkb, wvb, wob, relkp, nw4);

  proj_gemm<<<dim3(EE / 128, BB * LL / 128, 3), 256, 0, stream>>>(
      xq, xk, xv, wqb, wkb, wvb, bq, bk, bv, q_ws, k_ws, vt_ws);

  attn_fused<<<1024, 256, 0, stream>>>(q_ws, k_ws, vt_ws, relkp, rel_v, y_ws);

  out_gemm<<<dim3(EE / 128, BB * LL / 128), 256, 0, stream>>>(y_ws, wob, bo, (float*)d_out);
}